// Round 6
// baseline (236.811 us; speedup 1.0000x reference)
//
#include <hip/hip_runtime.h>

// Shapes fixed by the reference
#define BATCH 256
static const int N_IN0 = 20000, N_OUT0 = 8000;
static const int N_OUT1 = 2000, N_OUT2 = 500;

// ---------------- transpose (B x N) -> (N x B), 32x32 LDS tiles ----------------
__global__ void transpose_kernel(const float* __restrict__ in, float* __restrict__ out,
                                 int rows, int cols) {
    __shared__ float tile[32][33];  // +1 pad: no bank conflicts
    int c0 = blockIdx.x * 32, r0 = blockIdx.y * 32;
    int tx = threadIdx.x, ty = threadIdx.y;
    int c = c0 + tx, r = r0 + ty;
    if (r < rows && c < cols) tile[ty][tx] = in[(size_t)r * cols + c];
    __syncthreads();
    int oc = c0 + ty, orr = r0 + tx;
    if (oc < cols && orr < rows) out[(size_t)oc * rows + orr] = tile[tx][ty];
}

// ---------------- CSR build: histogram -> scan -> scatter ----------------
__global__ void hist_kernel(const int* __restrict__ rows, int E, int* __restrict__ counts) {
    int i = blockIdx.x * blockDim.x + threadIdx.x;
    if (i < E) atomicAdd(&counts[rows[i]], 1);
}

// single-block exclusive scan over n counts (n <= 8000); writes offsets[0..n] and cursor[0..n-1]
__global__ void scan_kernel(const int* __restrict__ counts, int n,
                            int* __restrict__ offsets, int* __restrict__ cursor) {
    __shared__ int sums[256];
    int t = threadIdx.x;
    int chunk = (n + 255) / 256;
    int begin = t * chunk;
    int end = begin + chunk; if (end > n) end = n;
    int s = 0;
    for (int i = begin; i < end; ++i) s += counts[i];
    sums[t] = s;
    __syncthreads();
    // Hillis-Steele inclusive scan of the 256 chunk sums
    for (int off = 1; off < 256; off <<= 1) {
        int u = (t >= off) ? sums[t - off] : 0;
        __syncthreads();
        sums[t] += u;
        __syncthreads();
    }
    int run = sums[t] - s;  // exclusive prefix of this chunk
    for (int i = begin; i < end; ++i) {
        offsets[i] = run;
        cursor[i] = run;
        run += counts[i];
    }
    if (t == 0) offsets[n] = sums[255];
}

__global__ void scatter_kernel(const int* __restrict__ rows, const int* __restrict__ cols,
                               const float* __restrict__ vals, int E,
                               int* __restrict__ cursor,
                               int* __restrict__ csr_col, float* __restrict__ csr_val) {
    int i = blockIdx.x * blockDim.x + threadIdx.x;
    if (i < E) {
        int p = atomicAdd(&cursor[rows[i]], 1);
        csr_col[p] = cols[i];
        csr_val[p] = vals[i];
    }
}

// ---------------- gather compute: one block (256 threads = batch) per output row ----------------
template <bool RELU, bool TRANS_OUT>
__global__ void gather_kernel(const float* __restrict__ xT, const int* __restrict__ offs,
                              const int* __restrict__ csr_col, const float* __restrict__ csr_val,
                              const float* __restrict__ bias, float* __restrict__ out, int n_out) {
    int r = blockIdx.x;
    int b = threadIdx.x;  // 0..255, contiguous lanes => coalesced xT reads
    int beg = offs[r], end = offs[r + 1];
    float acc = bias[r];
    int j = beg;
    for (; j + 3 < end; j += 4) {
        int c0 = csr_col[j], c1 = csr_col[j + 1], c2 = csr_col[j + 2], c3 = csr_col[j + 3];
        float v0 = csr_val[j], v1 = csr_val[j + 1], v2 = csr_val[j + 2], v3 = csr_val[j + 3];
        acc += xT[(size_t)c0 * BATCH + b] * v0;
        acc += xT[(size_t)c1 * BATCH + b] * v1;
        acc += xT[(size_t)c2 * BATCH + b] * v2;
        acc += xT[(size_t)c3 * BATCH + b] * v3;
    }
    for (; j < end; ++j) acc += xT[(size_t)csr_col[j] * BATCH + b] * csr_val[j];
    if (RELU) acc = fmaxf(acc, 0.f);
    if (TRANS_OUT) out[(size_t)r * BATCH + b] = acc;           // stay transposed (n_out x B)
    else out[(size_t)b * n_out + r] = acc;                     // final: (B x n_out) row-major
}

static inline size_t align256(size_t x) { return (x + 255) & ~(size_t)255; }

extern "C" void kernel_launch(void* const* d_in, const int* in_sizes, int n_in,
                              void* d_out, int out_size, void* d_ws, size_t ws_size,
                              hipStream_t stream) {
    const float* x    = (const float*)d_in[0];
    const int*  rows0 = (const int*)d_in[1];
    const int*  cols0 = (const int*)d_in[2];
    const float* vals0 = (const float*)d_in[3];
    const float* bias0 = (const float*)d_in[4];
    const int*  rows1 = (const int*)d_in[5];
    const int*  cols1 = (const int*)d_in[6];
    const float* vals1 = (const float*)d_in[7];
    const float* bias1 = (const float*)d_in[8];
    const int*  rows2 = (const int*)d_in[9];
    const int*  cols2 = (const int*)d_in[10];
    const float* vals2 = (const float*)d_in[11];
    const float* bias2 = (const float*)d_in[12];
    float* out = (float*)d_out;

    const int E0 = in_sizes[1], E1 = in_sizes[5], E2 = in_sizes[9];

    // ---- workspace carve-up (~34 MB) ----
    char* ws = (char*)d_ws;
    size_t off = 0;
    float* xT  = (float*)(ws + off); off = align256(off + (size_t)N_IN0 * BATCH * 4);
    float* h1  = (float*)(ws + off); off = align256(off + (size_t)N_OUT0 * BATCH * 4);
    float* h2  = (float*)(ws + off); off = align256(off + (size_t)N_OUT1 * BATCH * 4);

    int*   ccol0 = (int*)(ws + off);   off = align256(off + (size_t)E0 * 4);
    float* cval0 = (float*)(ws + off); off = align256(off + (size_t)E0 * 4);
    int*   ccol1 = (int*)(ws + off);   off = align256(off + (size_t)E1 * 4);
    float* cval1 = (float*)(ws + off); off = align256(off + (size_t)E1 * 4);
    int*   ccol2 = (int*)(ws + off);   off = align256(off + (size_t)E2 * 4);
    float* cval2 = (float*)(ws + off); off = align256(off + (size_t)E2 * 4);

    int* offs0 = (int*)(ws + off); off = align256(off + (size_t)(N_OUT0 + 1) * 4);
    int* offs1 = (int*)(ws + off); off = align256(off + (size_t)(N_OUT1 + 1) * 4);
    int* offs2 = (int*)(ws + off); off = align256(off + (size_t)(N_OUT2 + 1) * 4);
    int* cnt0  = (int*)(ws + off); off = align256(off + (size_t)N_OUT0 * 4);
    int* cnt1  = (int*)(ws + off); off = align256(off + (size_t)N_OUT1 * 4);
    int* cnt2  = (int*)(ws + off); off = align256(off + (size_t)N_OUT2 * 4);
    int* cur0  = (int*)(ws + off); off = align256(off + (size_t)N_OUT0 * 4);
    int* cur1  = (int*)(ws + off); off = align256(off + (size_t)N_OUT1 * 4);
    int* cur2  = (int*)(ws + off); off = align256(off + (size_t)N_OUT2 * 4);
    (void)ws_size; (void)out_size; (void)n_in;

    // ---- transpose x: (256 x 20000) -> (20000 x 256) ----
    {
        dim3 blk(32, 32);
        dim3 grd((N_IN0 + 31) / 32, (BATCH + 31) / 32);
        transpose_kernel<<<grd, blk, 0, stream>>>(x, xT, BATCH, N_IN0);
    }

    // ---- CSR builds (counts must be zeroed: ws is poisoned each call) ----
    hipMemsetAsync(cnt0, 0, (size_t)N_OUT0 * 4, stream);
    hipMemsetAsync(cnt1, 0, (size_t)N_OUT1 * 4, stream);
    hipMemsetAsync(cnt2, 0, (size_t)N_OUT2 * 4, stream);

    hist_kernel<<<(E0 + 255) / 256, 256, 0, stream>>>(rows0, E0, cnt0);
    hist_kernel<<<(E1 + 255) / 256, 256, 0, stream>>>(rows1, E1, cnt1);
    hist_kernel<<<(E2 + 255) / 256, 256, 0, stream>>>(rows2, E2, cnt2);

    scan_kernel<<<1, 256, 0, stream>>>(cnt0, N_OUT0, offs0, cur0);
    scan_kernel<<<1, 256, 0, stream>>>(cnt1, N_OUT1, offs1, cur1);
    scan_kernel<<<1, 256, 0, stream>>>(cnt2, N_OUT2, offs2, cur2);

    scatter_kernel<<<(E0 + 255) / 256, 256, 0, stream>>>(rows0, cols0, vals0, E0, cur0, ccol0, cval0);
    scatter_kernel<<<(E1 + 255) / 256, 256, 0, stream>>>(rows1, cols1, vals1, E1, cur1, ccol1, cval1);
    scatter_kernel<<<(E2 + 255) / 256, 256, 0, stream>>>(rows2, cols2, vals2, E2, cur2, ccol2, cval2);

    // ---- layer computes (atomic-free, coalesced gathers) ----
    gather_kernel<true,  true ><<<N_OUT0, BATCH, 0, stream>>>(xT, offs0, ccol0, cval0, bias0, h1, N_OUT0);
    gather_kernel<true,  true ><<<N_OUT1, BATCH, 0, stream>>>(h1, offs1, ccol1, cval1, bias1, h2, N_OUT1);
    gather_kernel<false, false><<<N_OUT2, BATCH, 0, stream>>>(h2, offs2, ccol2, cval2, bias2, out, N_OUT2);
}

// Round 9
// 171.826 us; speedup vs baseline: 1.3782x; 1.3782x over previous
//
#include <hip/hip_runtime.h>

// Shapes fixed by the reference
#define BATCH 256
#define CAP 128   // slots per output row; Poisson(32) mass above 128 ~ 1e-40
static const int N_IN0 = 20000, N_OUT0 = 8000;
static const int N_OUT1 = 2000, N_OUT2 = 500;

// ---------------- transpose (B x N) -> (N x B), 32x32 LDS tiles ----------------
__global__ void transpose_kernel(const float* __restrict__ in, float* __restrict__ out,
                                 int rows, int cols) {
    __shared__ float tile[32][33];  // +1 pad: no bank conflicts
    int c0 = blockIdx.x * 32, r0 = blockIdx.y * 32;
    int tx = threadIdx.x, ty = threadIdx.y;
    int c = c0 + tx, r = r0 + ty;
    if (r < rows && c < cols) tile[ty][tx] = in[(size_t)r * cols + c];
    __syncthreads();
    int oc = c0 + ty, orr = r0 + tx;
    if (oc < cols && orr < rows) out[(size_t)oc * rows + orr] = tile[tx][ty];
}

// ---------------- fused bucket scatter: all 3 layers in one dispatch ----------------
// cnt layout: [0,8000) layer0, [8000,10000) layer1, [10000,10500) layer2
__global__ void scatter_all(const int* __restrict__ rows0, const int* __restrict__ cols0,
                            const float* __restrict__ vals0, int E0,
                            const int* __restrict__ rows1, const int* __restrict__ cols1,
                            const float* __restrict__ vals1, int E1,
                            const int* __restrict__ rows2, const int* __restrict__ cols2,
                            const float* __restrict__ vals2, int E2,
                            int* __restrict__ cnt,
                            int2* __restrict__ slots0, int2* __restrict__ slots1,
                            int2* __restrict__ slots2) {
    int i = blockIdx.x * blockDim.x + threadIdx.x;
    if (i < E0) {
        int r = rows0[i];
        int p = atomicAdd(&cnt[r], 1);
        if (p < CAP) slots0[(size_t)r * CAP + p] = make_int2(cols0[i], __float_as_int(vals0[i]));
    } else if (i < E0 + E1) {
        int e = i - E0;
        int r = rows1[e];
        int p = atomicAdd(&cnt[N_OUT0 + r], 1);
        if (p < CAP) slots1[(size_t)r * CAP + p] = make_int2(cols1[e], __float_as_int(vals1[e]));
    } else if (i < E0 + E1 + E2) {
        int e = i - E0 - E1;
        int r = rows2[e];
        int p = atomicAdd(&cnt[N_OUT0 + N_OUT1 + r], 1);
        if (p < CAP) slots2[(size_t)r * CAP + p] = make_int2(cols2[e], __float_as_int(vals2[e]));
    }
}

// ---------------- gather compute: one block (256 threads = batch) per output row ----------------
template <bool RELU, bool TRANS_OUT>
__global__ void gather_kernel(const float* __restrict__ xT, const int* __restrict__ cnt,
                              const int2* __restrict__ slots,
                              const float* __restrict__ bias, float* __restrict__ out, int n_out) {
    int r = blockIdx.x;
    int b = threadIdx.x;  // 0..255, contiguous lanes => coalesced xT reads
    int n = cnt[r]; if (n > CAP) n = CAP;
    const int2* __restrict__ s = slots + (size_t)r * CAP;
    float acc = bias[r];
    int j = 0;
    for (; j + 3 < n; j += 4) {
        int2 e0 = s[j], e1 = s[j + 1], e2 = s[j + 2], e3 = s[j + 3];
        acc += xT[(size_t)e0.x * BATCH + b] * __int_as_float(e0.y);
        acc += xT[(size_t)e1.x * BATCH + b] * __int_as_float(e1.y);
        acc += xT[(size_t)e2.x * BATCH + b] * __int_as_float(e2.y);
        acc += xT[(size_t)e3.x * BATCH + b] * __int_as_float(e3.y);
    }
    for (; j < n; ++j) {
        int2 e = s[j];
        acc += xT[(size_t)e.x * BATCH + b] * __int_as_float(e.y);
    }
    if (RELU) acc = fmaxf(acc, 0.f);
    if (TRANS_OUT) out[(size_t)r * BATCH + b] = acc;           // stay transposed (n_out x B)
    else out[(size_t)b * n_out + r] = acc;                     // final: (B x n_out) row-major
}

static inline size_t align256(size_t x) { return (x + 255) & ~(size_t)255; }

extern "C" void kernel_launch(void* const* d_in, const int* in_sizes, int n_in,
                              void* d_out, int out_size, void* d_ws, size_t ws_size,
                              hipStream_t stream) {
    const float* x    = (const float*)d_in[0];
    const int*  rows0 = (const int*)d_in[1];
    const int*  cols0 = (const int*)d_in[2];
    const float* vals0 = (const float*)d_in[3];
    const float* bias0 = (const float*)d_in[4];
    const int*  rows1 = (const int*)d_in[5];
    const int*  cols1 = (const int*)d_in[6];
    const float* vals1 = (const float*)d_in[7];
    const float* bias1 = (const float*)d_in[8];
    const int*  rows2 = (const int*)d_in[9];
    const int*  cols2 = (const int*)d_in[10];
    const float* vals2 = (const float*)d_in[11];
    const float* bias2 = (const float*)d_in[12];
    float* out = (float*)d_out;

    const int E0 = in_sizes[1], E1 = in_sizes[5], E2 = in_sizes[9];
    const int NCNT = N_OUT0 + N_OUT1 + N_OUT2;  // 10500

    // ---- workspace carve-up (~42 MB) ----
    char* ws = (char*)d_ws;
    size_t off = 0;
    float* xT  = (float*)(ws + off); off = align256(off + (size_t)N_IN0 * BATCH * 4);
    float* h1  = (float*)(ws + off); off = align256(off + (size_t)N_OUT0 * BATCH * 4);
    float* h2  = (float*)(ws + off); off = align256(off + (size_t)N_OUT1 * BATCH * 4);
    int2* slots0 = (int2*)(ws + off); off = align256(off + (size_t)N_OUT0 * CAP * 8);
    int2* slots1 = (int2*)(ws + off); off = align256(off + (size_t)N_OUT1 * CAP * 8);
    int2* slots2 = (int2*)(ws + off); off = align256(off + (size_t)N_OUT2 * CAP * 8);
    int*  cnt    = (int*)(ws + off);  off = align256(off + (size_t)NCNT * 4);
    (void)ws_size; (void)out_size; (void)n_in;

    // ---- transpose x: (256 x 20000) -> (20000 x 256) ----
    {
        dim3 blk(32, 32);
        dim3 grd((N_IN0 + 31) / 32, (BATCH + 31) / 32);
        transpose_kernel<<<grd, blk, 0, stream>>>(x, xT, BATCH, N_IN0);
    }

    // ---- bucket CSR: one memset + one fused scatter (ws is re-poisoned each call) ----
    hipMemsetAsync(cnt, 0, (size_t)NCNT * 4, stream);
    {
        int total = E0 + E1 + E2;
        scatter_all<<<(total + 255) / 256, 256, 0, stream>>>(
            rows0, cols0, vals0, E0,
            rows1, cols1, vals1, E1,
            rows2, cols2, vals2, E2,
            cnt, slots0, slots1, slots2);
    }

    // ---- layer computes (atomic-free, coalesced gathers) ----
    gather_kernel<true,  true ><<<N_OUT0, BATCH, 0, stream>>>(xT, cnt,                   slots0, bias0, h1, N_OUT0);
    gather_kernel<true,  true ><<<N_OUT1, BATCH, 0, stream>>>(h1, cnt + N_OUT0,          slots1, bias1, h2, N_OUT1);
    gather_kernel<false, false><<<N_OUT2, BATCH, 0, stream>>>(h2, cnt + N_OUT0 + N_OUT1, slots2, bias2, out, N_OUT2);
}